// Round 2
// baseline (335.009 us; speedup 1.0000x reference)
//
#include <hip/hip_runtime.h>
#include <hip/hip_bf16.h>
#include <hip/hip_fp16.h>

typedef _Float16 half8 __attribute__((ext_vector_type(8)));
typedef float f32x4 __attribute__((ext_vector_type(4)));
typedef float f32x2 __attribute__((ext_vector_type(2)));

// ---------------- helpers ----------------
static __device__ __forceinline__ float bf2f_lo(unsigned u) {
    return __uint_as_float(u << 16);
}
static __device__ __forceinline__ float bf2f_hi(unsigned u) {
    return __uint_as_float(u & 0xffff0000u);
}
static __device__ __forceinline__ unsigned f2bf_rne_bits(float f) {
    unsigned u = __float_as_uint(f);
    return u + 0x7fffu + ((u >> 16) & 1u);
}
static __device__ __forceinline__ unsigned pack_bf2(float a, float b) {
    return (f2bf_rne_bits(a) >> 16) | (f2bf_rne_bits(b) & 0xffff0000u);
}

// ================= CSR build: two-level bucket sort =================
#define CHUNK 4096

__global__ void kb_zero(int* bucketCount, int NBK) {
    int i = blockIdx.x * 256 + threadIdx.x;
    if (i < NBK) bucketCount[i] = 0;
}

__global__ void kb_count(const int* __restrict__ dst, int* bucketCount,
                         int E, int T, int NBK) {
    __shared__ int cnt[256];
    const int tid = threadIdx.x;
    const int beg = blockIdx.x * CHUNK;
    const int end = min(beg + CHUNK, T);
    cnt[tid] = 0;
    __syncthreads();
    for (int i = beg + tid; i < end; i += 256) {
        int d = (i < E) ? dst[i] : (i - E);
        atomicAdd(&cnt[d >> 8], 1);
    }
    __syncthreads();
    if (tid < NBK && cnt[tid] > 0) atomicAdd(&bucketCount[tid], cnt[tid]);
}

__global__ void kb_scan(const int* __restrict__ bucketCount, int* bucketBase,
                        int* bucketCursor, int* row_ptr, int NBK, int N, int total) {
    __shared__ int sm[256];
    const int tid = threadIdx.x;
    int v = (tid < NBK) ? bucketCount[tid] : 0;
    sm[tid] = v;
    __syncthreads();
    for (int off = 1; off < 256; off <<= 1) {
        int t = (tid >= off) ? sm[tid - off] : 0;
        __syncthreads();
        sm[tid] += t;
        __syncthreads();
    }
    if (tid < NBK) {
        int ex = sm[tid] - v;
        bucketBase[tid] = ex;
        bucketCursor[tid] = ex;
    }
    if (tid == 0) {
        bucketBase[NBK] = total;
        row_ptr[N] = total;
    }
}

__global__ void kb_place(const int* __restrict__ src, const int* __restrict__ dst,
                         int* bucketCursor, unsigned* __restrict__ barr,
                         int E, int T, int NBK) {
    __shared__ int cnt[256];
    __shared__ int wb[256];
    const int tid = threadIdx.x;
    const int beg = blockIdx.x * CHUNK;
    const int end = min(beg + CHUNK, T);
    cnt[tid] = 0;
    __syncthreads();
    for (int i = beg + tid; i < end; i += 256) {
        int d = (i < E) ? dst[i] : (i - E);
        atomicAdd(&cnt[d >> 8], 1);
    }
    __syncthreads();
    if (tid < NBK) {
        int c = cnt[tid];
        wb[tid] = (c > 0) ? atomicAdd(&bucketCursor[tid], c) : 0;
    }
    __syncthreads();
    cnt[tid] = 0;
    __syncthreads();
    for (int i = beg + tid; i < end; i += 256) {
        int s, d;
        if (i < E) { s = src[i]; d = dst[i]; }
        else       { s = i - E;  d = s; }
        int g = d >> 8;
        unsigned pk = (unsigned)s | ((unsigned)(d & 255) << 16);
        int r = atomicAdd(&cnt[g], 1);
        barr[wb[g] + r] = pk;
    }
}

__global__ void kb_csr(const unsigned* __restrict__ barr, const int* __restrict__ bucketBase,
                       int* __restrict__ row_ptr, int* __restrict__ col, int N) {
    __shared__ int cnt[256];
    __shared__ int sm[256];
    __shared__ int cur[256];
    const int tid = threadIdx.x;
    const int b = blockIdx.x;
    const int beg = bucketBase[b];
    const int end = bucketBase[b + 1];
    cnt[tid] = 0;
    __syncthreads();
    for (int i = beg + tid; i < end; i += 256)
        atomicAdd(&cnt[barr[i] >> 16], 1);
    __syncthreads();
    int v = cnt[tid];
    sm[tid] = v;
    __syncthreads();
    for (int off = 1; off < 256; off <<= 1) {
        int t = (tid >= off) ? sm[tid - off] : 0;
        __syncthreads();
        sm[tid] += t;
        __syncthreads();
    }
    int ex = sm[tid] - v;
    int n = b * 256 + tid;
    if (n < N) row_ptr[n] = beg + ex;
    cur[tid] = beg + ex;
    __syncthreads();
    for (int i = beg + tid; i < end; i += 256) {
        unsigned p = barr[i];
        int pos = atomicAdd(&cur[p >> 16], 1);
        col[pos] = (int)(p & 0xFFFFu);
    }
}

// ---------------- MFMA GEMM: h = A @ W (fp32 in, bf16 out) + alpha epilogue ----
// Output now stored as HEAD-SPLIT planes: Hout[hh][row][16 dwords] (64B head
// slice per row) so the aggregation can pin each 3.2MB plane to one XCD's L2.
// asrc/adst likewise stored as [H][N] planes.
__launch_bounds__(256)
__global__ void k_gemm(const float* __restrict__ A, const float* __restrict__ W,
                       const float* __restrict__ a_src, const float* __restrict__ a_dst,
                       unsigned* __restrict__ Hout,
                       float* __restrict__ asrc_o, float* __restrict__ adst_o,
                       int nrows, int ntiles) {
    __shared__ _Float16 Wt[128 * 136];  // [c][k], stride 136 (272B = 16*17, b128-aligned)
    const int tid = threadIdx.x;
    // stage W^T (fp32 [k][c] -> fp16 [c][k]), coalesced global reads
    for (int idx = tid; idx < 128 * 128 / 4; idx += 256) {
        int k = idx >> 5;            // 32 float4 per k-row
        int c4 = (idx & 31) * 4;
        float4 v = *(const float4*)&W[(size_t)k * 128 + c4];
        Wt[(c4 + 0) * 136 + k] = (_Float16)v.x;
        Wt[(c4 + 1) * 136 + k] = (_Float16)v.y;
        Wt[(c4 + 2) * 136 + k] = (_Float16)v.z;
        Wt[(c4 + 3) * 136 + k] = (_Float16)v.w;
    }
    __syncthreads();
    const int lane = tid & 63;
    const int m = lane & 15, quad = lane >> 4;

    // W fragments -> registers: wf[ks][ct] = A-op[mA=lane&15][k=quad*8+j]
    half8 wf[4][8];
#pragma unroll
    for (int ks = 0; ks < 4; ++ks)
#pragma unroll
        for (int ct = 0; ct < 8; ++ct)
            wf[ks][ct] = *(half8*)&Wt[(ct * 16 + m) * 136 + ks * 32 + quad * 8];

    const int wv = (blockIdx.x * 256 + tid) >> 6;
    const int nwaves = gridDim.x * 4;
    for (int t = wv; t < ntiles; t += nwaves) {
        const int row = t * 16 + m;
        const int rc = min(row, nrows - 1);
        const float* ap = A + (size_t)rc * 128;
        f32x4 acc[8];
#pragma unroll
        for (int ct = 0; ct < 8; ++ct) acc[ct] = (f32x4){0.f, 0.f, 0.f, 0.f};
#pragma unroll
        for (int ks = 0; ks < 4; ++ks) {
            float4 x0 = *(const float4*)&ap[ks * 32 + quad * 8];
            float4 x1 = *(const float4*)&ap[ks * 32 + quad * 8 + 4];
            half8 af;
            af[0] = (_Float16)x0.x; af[1] = (_Float16)x0.y;
            af[2] = (_Float16)x0.z; af[3] = (_Float16)x0.w;
            af[4] = (_Float16)x1.x; af[5] = (_Float16)x1.y;
            af[6] = (_Float16)x1.z; af[7] = (_Float16)x1.w;
#pragma unroll
            for (int ct = 0; ct < 8; ++ct)
                acc[ct] = __builtin_amdgcn_mfma_f32_16x16x32_f16(wf[ks][ct], af, acc[ct], 0, 0, 0);
        }
        // h store: head-split planes. ct covers cols [ct*16, ct*16+16):
        // head = ct>>1, within-head dword offset = (ct&1)*8 + quad*2
        if (row < nrows) {
#pragma unroll
            for (int ct = 0; ct < 8; ++ct) {
                uint2 o;
                o.x = pack_bf2(acc[ct][0], acc[ct][1]);
                o.y = pack_bf2(acc[ct][2], acc[ct][3]);
                *(uint2*)&Hout[((size_t)(ct >> 1) * nrows + row) * 16 + (ct & 1) * 8 + quad * 2] = o;
            }
        }
        // alpha partials (fp32, pre-rounding); a_src/a_dst are L1-hot (512B)
        float ps[4] = {0.f, 0.f, 0.f, 0.f}, pd[4] = {0.f, 0.f, 0.f, 0.f};
#pragma unroll
        for (int ct = 0; ct < 8; ++ct) {
            int hh = ct >> 1;
#pragma unroll
            for (int r = 0; r < 4; ++r) {
                int c = ct * 16 + quad * 4 + r;
                ps[hh] += acc[ct][r] * a_src[c];
                pd[hh] += acc[ct][r] * a_dst[c];
            }
        }
#pragma unroll
        for (int hh = 0; hh < 4; ++hh) {
            ps[hh] += __shfl_xor(ps[hh], 16); ps[hh] += __shfl_xor(ps[hh], 32);
            pd[hh] += __shfl_xor(pd[hh], 16); pd[hh] += __shfl_xor(pd[hh], 32);
        }
        if (row < nrows) {
            asrc_o[(size_t)quad * nrows + row] = ps[quad];  // [H][N] plane
            adst_o[(size_t)quad * nrows + row] = pd[quad];
        }
    }
}

// ---------------- fused softmax-aggregate + bias + ELU (R7: XCD-pinned) -------
// Grid: blockIdx&7 -> (head hh = &3, dst-half inst = >>2). With round-robin
// block->XCD dispatch, all blocks touching head-plane hh land on XCDs {hh,hh+4},
// so the 3.2MB plane is L2-resident -> gathers are L2 hits, not L3 misses.
// Wave layout: 4 dsts (lane>>4) x 4 edge slots ((lane>>2)&3) x 4 lanes/edge
// (lane&3, 16B each of the 64B head slice). p recomputed per head (lane-local,
// fp32, no shuffles); epilogue reduce is only 2 butterfly levels (xor 4,8).
__launch_bounds__(256)
__global__ void k_aggr(const unsigned* __restrict__ h,    // [4][N][16] dwords
                       const float* __restrict__ asrc,    // [4][N]
                       const float* __restrict__ adst,    // [4][N]
                       const float* __restrict__ bias,
                       const int* __restrict__ row_ptr, const int* __restrict__ col,
                       float* __restrict__ out, int N, int CPI) {
    const int g8 = blockIdx.x & 7;
    const int hh = g8 & 3;
    const int inst = g8 >> 2;
    const int chunk = blockIdx.x >> 3;
    const int lane = threadIdx.x & 63;
    const int dst_sub = lane >> 4;
    const int eb2 = (lane >> 2) & 3;
    const int q = lane & 3;

    const int d = ((inst * CPI + chunk) * 4 + (threadIdx.x >> 6)) * 4 + dst_sub;
    const int dc = min(d, N - 1);
    const unsigned* __restrict__ hp = h + (size_t)hh * N * 16;
    const float* __restrict__ as = asrc + (size_t)hh * N;
    const float adv = adst[(size_t)hh * N + dc];
    const int beg = row_ptr[dc];
    const int end = row_ptr[dc + 1];

    // uniform iteration count = max over the wave's 4 dsts
    int its = (end - beg + 3) >> 2;
    its = max(its, __shfl_xor(its, 16));
    its = max(its, __shfl_xor(its, 32));

    f32x2 acc[4];
#pragma unroll
    for (int i = 0; i < 4; ++i) acc[i] = (f32x2){0.f, 0.f};
    float sp = 0.f;

    int idx = beg + eb2;
    int cv = col[min(idx, end - 1)];
    float av = as[cv];
    uint4 u = *(const uint4*)&hp[(size_t)(unsigned)cv * 16 + q * 4];

    for (int it = 0; it < its - 1; ++it) {
        // prefetch next slot (clamped addresses stay L2-hot)
        int idx2 = idx + 4;
        int cv2 = col[min(idx2, end - 1)];
        float av2 = as[cv2];
        uint4 u2 = *(const uint4*)&hp[(size_t)(unsigned)cv2 * 16 + q * 4];
        float e = av + adv;
        e = fmaxf(e, 0.2f * e);
        float p = (idx < end) ? __expf(e) : 0.f;
        sp += p;
        f32x2 pv = {p, p};
        acc[0] = __builtin_elementwise_fma((f32x2){bf2f_lo(u.x), bf2f_hi(u.x)}, pv, acc[0]);
        acc[1] = __builtin_elementwise_fma((f32x2){bf2f_lo(u.y), bf2f_hi(u.y)}, pv, acc[1]);
        acc[2] = __builtin_elementwise_fma((f32x2){bf2f_lo(u.z), bf2f_hi(u.z)}, pv, acc[2]);
        acc[3] = __builtin_elementwise_fma((f32x2){bf2f_lo(u.w), bf2f_hi(u.w)}, pv, acc[3]);
        idx = idx2; cv = cv2; av = av2; u = u2;
    }
    {   // last iteration (no prefetch)
        float e = av + adv;
        e = fmaxf(e, 0.2f * e);
        float p = (idx < end) ? __expf(e) : 0.f;
        sp += p;
        f32x2 pv = {p, p};
        acc[0] = __builtin_elementwise_fma((f32x2){bf2f_lo(u.x), bf2f_hi(u.x)}, pv, acc[0]);
        acc[1] = __builtin_elementwise_fma((f32x2){bf2f_lo(u.y), bf2f_hi(u.y)}, pv, acc[1]);
        acc[2] = __builtin_elementwise_fma((f32x2){bf2f_lo(u.z), bf2f_hi(u.z)}, pv, acc[2]);
        acc[3] = __builtin_elementwise_fma((f32x2){bf2f_lo(u.w), bf2f_hi(u.w)}, pv, acc[3]);
    }

    // reduce over the 4 edge slots (lane bits 2,3)
#pragma unroll
    for (int off = 4; off <= 8; off <<= 1) {
        sp += __shfl_xor(sp, off);
#pragma unroll
        for (int i = 0; i < 4; ++i) {
            acc[i][0] += __shfl_xor(acc[i][0], off);
            acc[i][1] += __shfl_xor(acc[i][1], off);
        }
    }

    if (eb2 == 0 && d < N) {
        float inv = 1.f / sp;
        int cb = hh * 32 + q * 8;
        float vv[8];
#pragma unroll
        for (int i = 0; i < 4; ++i) {
            vv[2 * i]     = acc[i][0] * inv + bias[cb + 2 * i];
            vv[2 * i + 1] = acc[i][1] * inv + bias[cb + 2 * i + 1];
        }
#pragma unroll
        for (int i = 0; i < 8; ++i) vv[i] = (vv[i] > 0.f) ? vv[i] : (__expf(vv[i]) - 1.f);
        *(float4*)&out[(size_t)d * 128 + cb]     = make_float4(vv[0], vv[1], vv[2], vv[3]);
        *(float4*)&out[(size_t)d * 128 + cb + 4] = make_float4(vv[4], vv[5], vv[6], vv[7]);
    }
}

// ---------------- launch ----------------
extern "C" void kernel_launch(void* const* d_in, const int* in_sizes, int n_in,
                              void* d_out, int out_size, void* d_ws, size_t ws_size,
                              hipStream_t stream) {
    const float* x      = (const float*)d_in[0];
    const int*   ei     = (const int*)d_in[1];
    const float* W1     = (const float*)d_in[2];
    const float* a_src1 = (const float*)d_in[3];
    const float* a_dst1 = (const float*)d_in[4];
    const float* b1     = (const float*)d_in[5];
    const float* W2     = (const float*)d_in[6];
    const float* a_src2 = (const float*)d_in[7];
    const float* a_dst2 = (const float*)d_in[8];
    const float* b2     = (const float*)d_in[9];

    const int N = in_sizes[0] / 128;
    const int E = in_sizes[1] / 2;
    const int T = E + N;
    const int NBK = (N + 255) / 256;
    const int* src = ei;
    const int* dst = ei + E;

    char* w = (char*)d_ws;
    auto alloc = [&](size_t bytes) -> char* {
        char* p = w;
        w += (bytes + 255) & ~(size_t)255;
        return p;
    };
    unsigned* h_bf    = (unsigned*)alloc((size_t)N * 64 * 4);
    float*    o1      = (float*)alloc((size_t)N * 128 * 4);
    float*    asrc    = (float*)alloc((size_t)N * 4 * 4);
    float*    adst    = (float*)alloc((size_t)N * 4 * 4);
    int*      row_ptr = (int*)alloc((size_t)(N + 1) * 4);
    int*      col     = (int*)alloc((size_t)T * 4);
    int*      bCount  = (int*)alloc((size_t)NBK * 4);
    int*      bBase   = (int*)alloc((size_t)(NBK + 1) * 4);
    int*      bCursor = (int*)alloc((size_t)NBK * 4);
    unsigned* barr    = (unsigned*)o1;   // alias: dead before o1 written
    (void)ws_size; (void)n_in; (void)out_size;

    const int PB = (T + CHUNK - 1) / CHUNK;

    hipLaunchKernelGGL(kb_zero, dim3((NBK + 255) / 256), dim3(256), 0, stream, bCount, NBK);
    hipLaunchKernelGGL(kb_count, dim3(PB), dim3(256), 0, stream, dst, bCount, E, T, NBK);
    hipLaunchKernelGGL(kb_scan, dim3(1), dim3(256), 0, stream, bCount, bBase, bCursor, row_ptr, NBK, N, T);
    hipLaunchKernelGGL(kb_place, dim3(PB), dim3(256), 0, stream, src, dst, bCursor, barr, E, T, NBK);
    hipLaunchKernelGGL(kb_csr, dim3(NBK), dim3(256), 0, stream, barr, bBase, row_ptr, col, N);

    const int ntiles = (N + 15) / 16;
    const int GB = 512;               // grid-stride over tiles (2048 waves)
    const int CPB = (N + 15) / 16;    // 16-dst chunks
    const int CPI = (CPB + 1) / 2;    // chunks per XCD instance (2 XCDs per head)
    const int AB = 8 * CPI;           // bid&7 selects (head, dst-half)

    hipLaunchKernelGGL(k_gemm, dim3(GB), dim3(256), 0, stream, x, W1, a_src1, a_dst1, h_bf, asrc, adst, N, ntiles);
    hipLaunchKernelGGL(k_aggr, dim3(AB), dim3(256), 0, stream, h_bf, asrc, adst, b1, row_ptr, col, o1, N, CPI);
    hipLaunchKernelGGL(k_gemm, dim3(GB), dim3(256), 0, stream, o1, W2, a_src2, a_dst2, h_bf, asrc, adst, N, ntiles);
    hipLaunchKernelGGL(k_aggr, dim3(AB), dim3(256), 0, stream, h_bf, asrc, adst, b2, row_ptr, col, (float*)d_out, N, CPI);
}